// Round 13
// baseline (8588.634 us; speedup 1.0000x reference)
//
#include <hip/hip_runtime.h>
#include <stdint.h>

typedef _Float16 f16;
typedef f16 half8 __attribute__((ext_vector_type(8)));
typedef float f32x4 __attribute__((ext_vector_type(4)));
typedef unsigned long long u64;

constexpr int HID = 1024;
constexpr int NBAT = 128;
constexpr int SEQ = 256;
constexpr int NL0 = 64;          // layer0 blocks: 16 units, K=1024
constexpr int NL1 = 128;         // layer1 blocks: 8 units,  K=2048 ([Wih1|Whh1])
constexpr int NBLK = NL0 + NL1;  // 192
constexpr int HROWB = 4096;      // Hcat row bytes: [h0(1024) | h1(1024)] f16
constexpr int WROWB0 = 2064;     // L0 LDS W row: 2048B + 16 pad
constexpr int WROWB1 = 4112;     // L1 LDS W row: 4096B + 16 pad
constexpr int ZOFF = 32 * WROWB1;    // 131584: start of shared zero band (L1)
constexpr int ZBYTES = 4160;         // covers ck*64 + lhi*16 (<= 4080) + slack
constexpr int WLDS = ZOFF + ZBYTES;  // 135744 >= 64*WROWB0 (132096)
constexpr int LDS_TOTAL = WLDS;      // no LDS staging

// sync buffer layout (ints; 128B line separation)
constexpr int SY_INIT = 0;          // one-time init barrier
constexpr int SY_BARG = 32;         // global "XCD flushed" counter (accumulating)
constexpr int SY_CNT = 64;          // +32*x: blocks on XCD x
constexpr int SY_BARAX = 64 + 256;  // +32*x: per-XCD arrivals (accumulating)

__device__ __forceinline__ float sigm(float x) { return 1.0f / (1.0f + __expf(-x)); }
__device__ __forceinline__ float tanh_(float x) {
  float e = __expf(2.0f * x);
  return (e - 1.0f) / (e + 1.0f);
}
__device__ __forceinline__ void vm0() {
  asm volatile("s_waitcnt vmcnt(0)" ::: "memory");
}
// agent-scope atomic load: bypasses L1/L2, reads LLC-fresh data (proven by
// every spin loop in rounds 2-12). Compiler tracks it like a normal load
// (auto vmcnt scheduling, prefetch-ahead in unrolled rings).
__device__ __forceinline__ u64 ald(const void* p) {
  return __hip_atomic_load((const u64*)p, __ATOMIC_RELAXED, __HIP_MEMORY_SCOPE_AGENT);
}
__device__ __forceinline__ void spin_until(int* p, int target) {
  uint64_t t0 = __builtin_amdgcn_s_memtime();
  while (__hip_atomic_load(p, __ATOMIC_RELAXED, __HIP_MEMORY_SCOPE_AGENT) < target) {
    __builtin_amdgcn_s_sleep(1);
    if (__builtin_amdgcn_s_memtime() - t0 > (1ULL << 29)) break;  // bounded on pathology
  }
}

union cv16 { u64 q[2]; half8 h; };

__global__ __launch_bounds__(256, 1) void lstm_persist(
    const float* __restrict__ X,
    const float* __restrict__ Wih0, const float* __restrict__ Whh0,
    const float* __restrict__ bih0, const float* __restrict__ bhh0,
    const float* __restrict__ Wih1, const float* __restrict__ Whh1,
    const float* __restrict__ bih1, const float* __restrict__ bhh1,
    const float* __restrict__ Wlin,
    f16* __restrict__ Hcat,   // [2][128][2048]  ([h0|h1] per row, parity slots)
    float* __restrict__ yp,   // [256][128][128] per-L1-block y partials
    int* __restrict__ sy) {
  extern __shared__ char smem[];
  char* Wl = smem;

  const int bid = blockIdx.x, tid = threadIdx.x;
  const bool isL0 = bid < NL0;
  const int j = isL0 ? bid : bid - NL0;
  const int w = tid >> 6, l = tid & 63;
  const int l15 = l & 15, lhi = l >> 4;

  int xcd;
  asm volatile("s_getreg_b32 %0, hwreg(HW_REG_XCC_ID)" : "=s"(xcd));
  xcd &= 7;

  // ---- one-time W preload: f32 global -> f16 LDS (padded rows) ----
  if (isL0) {
    for (int it = 0; it < 256; ++it) {
      int e = it * 256 + tid;
      int r = e >> 10, k = e & 1023;                 // LDS row r = gate*16 + u
      int grow = (r >> 4) * HID + j * 16 + (r & 15);
      *(f16*)(Wl + r * WROWB0 + 2 * k) = (f16)Whh0[(size_t)grow * HID + k];
    }
  } else {
    for (int it = 0; it < 256; ++it) {
      int e = it * 256 + tid;
      int r = e >> 11, k = e & 2047;                 // LDS row r = gate*8 + u
      int grow = (r >> 3) * HID + j * 8 + (r & 7);
      float v = (k < 1024) ? Wih1[(size_t)grow * HID + k]
                           : Whh1[(size_t)grow * HID + (k - 1024)];
      *(f16*)(Wl + r * WROWB1 + 2 * k) = (f16)v;
    }
    for (int e = tid; e < ZBYTES / 2; e += 256)      // shared zero band (N-pad)
      *(f16*)(Wl + ZOFF + 2 * e) = (f16)0.f;
  }

  // ---- per-lane constants ----
  float bi, bf, bg, bo, wi_i = 0, wi_f = 0, wi_g = 0, wi_o = 0, wl = 0;
  if (isL0) {
    int m = j * 16 + l15;
    bi = bih0[m] + bhh0[m];
    bf = bih0[HID + m] + bhh0[HID + m];
    bg = bih0[2 * HID + m] + bhh0[2 * HID + m];
    bo = bih0[3 * HID + m] + bhh0[3 * HID + m];
    wi_i = Wih0[m]; wi_f = Wih0[HID + m];
    wi_g = Wih0[2 * HID + m]; wi_o = Wih0[3 * HID + m];
  } else {
    int u = j * 8 + (l15 & 7);
    bi = bih1[u] + bhh1[u];
    bf = bih1[HID + u] + bhh1[HID + u];
    bg = bih1[2 * HID + u] + bhh1[2 * HID + u];
    bo = bih1[3 * HID + u] + bhh1[3 * HID + u];
    wl = (l15 < 8) ? Wlin[u] : 0.f;  // pad lanes contribute 0 to y
  }
  float cst[8];
#pragma unroll
  for (int q = 0; q < 8; ++q) cst[q] = 0.f;

  // ---- init: learn per-XCD block count cx and XCD count nx (one-time) ----
  int cx = 0, nx = 0;
  if (tid == 0) {
    __hip_atomic_fetch_add(&sy[SY_CNT + 32 * xcd], 1, __ATOMIC_RELAXED,
                           __HIP_MEMORY_SCOPE_AGENT);
    __hip_atomic_fetch_add(&sy[SY_INIT], 1, __ATOMIC_RELAXED, __HIP_MEMORY_SCOPE_AGENT);
    spin_until(&sy[SY_INIT], NBLK);
    cx = __hip_atomic_load(&sy[SY_CNT + 32 * xcd], __ATOMIC_RELAXED,
                           __HIP_MEMORY_SCOPE_AGENT);
#pragma unroll
    for (int x = 0; x < 8; ++x)
      nx += (__hip_atomic_load(&sy[SY_CNT + 32 * x], __ATOMIC_RELAXED,
                               __HIP_MEMORY_SCOPE_AGENT) > 0);
  }
  __syncthreads();

  // L0 B pointers: proven 16-unit layout (b tiles at +16/32/48 rows)
  const char* Wb = Wl + l15 * WROWB0 + lhi * 16;
  // L1 B pointers: one per gate; cols 8-15 -> shared zero band (B-frag = 0)
  const char* Wg0 = Wl + ((l15 < 8) ? (0 * 8 + l15) * WROWB1 : ZOFF) + lhi * 16;
  const char* Wg1 = Wl + ((l15 < 8) ? (1 * 8 + l15) * WROWB1 : ZOFF) + lhi * 16;
  const char* Wg2 = Wl + ((l15 < 8) ? (2 * 8 + l15) * WROWB1 : ZOFF) + lhi * 16;
  const char* Wg3 = Wl + ((l15 < 8) ? (3 * 8 + l15) * WROWB1 : ZOFF) + lhi * 16;

  for (int i = 1; i <= SEQ + 1; ++i) {
    const bool active = isL0 ? (i <= SEQ) : (i >= 2);
    if (active) {
      const char* Asrc = (const char*)Hcat + (size_t)((i - 1) & 1) * NBAT * HROWB;
      // per-lane A-fragment pointers: one 16B fragment (= 2 u64) per chunk
      const char* a0p = Asrc + (size_t)(32 * w + l15) * HROWB + lhi * 16;
      const char* a1p = a0p + (size_t)16 * HROWB;
      f16* Hw = Hcat + (size_t)(i & 1) * NBAT * 2048;

      if (isL0) {
        // -------- layer0: 0-idx step i-1, K=1024 (h0 half), 4 gate-tiles --------
        float xr[8];
#pragma unroll
        for (int mf = 0; mf < 2; ++mf)
#pragma unroll
          for (int r = 0; r < 4; ++r)
            xr[mf * 4 + r] = X[(32 * w + 16 * mf + 4 * lhi + r) * SEQ + (i - 1)];

        u64 qa0[8], qa1[8], qb0[8], qb1[8];
#pragma unroll
        for (int k0 = 0; k0 < 8; ++k0) {
          qa0[k0] = ald(a0p + k0 * 64);
          qa1[k0] = ald(a0p + k0 * 64 + 8);
          qb0[k0] = ald(a1p + k0 * 64);
          qb1[k0] = ald(a1p + k0 * 64 + 8);
        }
        f32x4 acc[2][4];
#pragma unroll
        for (int mf = 0; mf < 2; ++mf)
#pragma unroll
          for (int n = 0; n < 4; ++n) acc[mf][n] = f32x4{0.f, 0.f, 0.f, 0.f};

#pragma unroll
        for (int ck = 0; ck < 32; ++ck) {
          cv16 ca, cb;
          ca.q[0] = qa0[ck & 7]; ca.q[1] = qa1[ck & 7];
          cb.q[0] = qb0[ck & 7]; cb.q[1] = qb1[ck & 7];
          if (ck < 24) {
            qa0[ck & 7] = ald(a0p + (ck + 8) * 64);
            qa1[ck & 7] = ald(a0p + (ck + 8) * 64 + 8);
            qb0[ck & 7] = ald(a1p + (ck + 8) * 64);
            qb1[ck & 7] = ald(a1p + (ck + 8) * 64 + 8);
          }
          half8 a0 = ca.h, a1 = cb.h;
          half8 b0 = *(const half8*)(Wb + ck * 64);
          half8 b1 = *(const half8*)(Wb + 16 * WROWB0 + ck * 64);
          half8 b2 = *(const half8*)(Wb + 32 * WROWB0 + ck * 64);
          half8 b3 = *(const half8*)(Wb + 48 * WROWB0 + ck * 64);
          acc[0][0] = __builtin_amdgcn_mfma_f32_16x16x32_f16(a0, b0, acc[0][0], 0, 0, 0);
          acc[0][1] = __builtin_amdgcn_mfma_f32_16x16x32_f16(a0, b1, acc[0][1], 0, 0, 0);
          acc[0][2] = __builtin_amdgcn_mfma_f32_16x16x32_f16(a0, b2, acc[0][2], 0, 0, 0);
          acc[0][3] = __builtin_amdgcn_mfma_f32_16x16x32_f16(a0, b3, acc[0][3], 0, 0, 0);
          acc[1][0] = __builtin_amdgcn_mfma_f32_16x16x32_f16(a1, b0, acc[1][0], 0, 0, 0);
          acc[1][1] = __builtin_amdgcn_mfma_f32_16x16x32_f16(a1, b1, acc[1][1], 0, 0, 0);
          acc[1][2] = __builtin_amdgcn_mfma_f32_16x16x32_f16(a1, b2, acc[1][2], 0, 0, 0);
          acc[1][3] = __builtin_amdgcn_mfma_f32_16x16x32_f16(a1, b3, acc[1][3], 0, 0, 0);
        }

#pragma unroll
        for (int mf = 0; mf < 2; ++mf) {
#pragma unroll
          for (int r = 0; r < 4; ++r) {
            int b = 32 * w + 16 * mf + 4 * lhi + r;
            float xv = xr[mf * 4 + r];
            float gi = acc[mf][0][r] + bi + xv * wi_i;
            float gf = acc[mf][1][r] + bf + xv * wi_f;
            float gg = acc[mf][2][r] + bg + xv * wi_g;
            float go = acc[mf][3][r] + bo + xv * wi_o;
            float cn = sigm(gf) * cst[mf * 4 + r] + sigm(gi) * tanh_(gg);
            float hn = sigm(go) * tanh_(cn);
            cst[mf * 4 + r] = cn;
            Hw[(size_t)b * 2048 + j * 16 + l15] = (f16)hn;
          }
        }
      } else {
        // ---- layer1: 0-idx step i-2, K=2048 full [h0|h1] row, 4 gate-tiles ----
        u64 qa0[8], qa1[8], qb0[8], qb1[8];
#pragma unroll
        for (int k0 = 0; k0 < 8; ++k0) {
          qa0[k0] = ald(a0p + k0 * 64);
          qa1[k0] = ald(a0p + k0 * 64 + 8);
          qb0[k0] = ald(a1p + k0 * 64);
          qb1[k0] = ald(a1p + k0 * 64 + 8);
        }
        f32x4 acc[2][4];
#pragma unroll
        for (int mf = 0; mf < 2; ++mf)
#pragma unroll
          for (int n = 0; n < 4; ++n) acc[mf][n] = f32x4{0.f, 0.f, 0.f, 0.f};

#pragma unroll
        for (int ck = 0; ck < 64; ++ck) {
          cv16 ca, cb;
          ca.q[0] = qa0[ck & 7]; ca.q[1] = qa1[ck & 7];
          cb.q[0] = qb0[ck & 7]; cb.q[1] = qb1[ck & 7];
          if (ck < 56) {
            qa0[ck & 7] = ald(a0p + (ck + 8) * 64);
            qa1[ck & 7] = ald(a0p + (ck + 8) * 64 + 8);
            qb0[ck & 7] = ald(a1p + (ck + 8) * 64);
            qb1[ck & 7] = ald(a1p + (ck + 8) * 64 + 8);
          }
          half8 a0 = ca.h, a1 = cb.h;
          half8 b0 = *(const half8*)(Wg0 + ck * 64);
          half8 b1 = *(const half8*)(Wg1 + ck * 64);
          half8 b2 = *(const half8*)(Wg2 + ck * 64);
          half8 b3 = *(const half8*)(Wg3 + ck * 64);
          acc[0][0] = __builtin_amdgcn_mfma_f32_16x16x32_f16(a0, b0, acc[0][0], 0, 0, 0);
          acc[0][1] = __builtin_amdgcn_mfma_f32_16x16x32_f16(a0, b1, acc[0][1], 0, 0, 0);
          acc[0][2] = __builtin_amdgcn_mfma_f32_16x16x32_f16(a0, b2, acc[0][2], 0, 0, 0);
          acc[0][3] = __builtin_amdgcn_mfma_f32_16x16x32_f16(a0, b3, acc[0][3], 0, 0, 0);
          acc[1][0] = __builtin_amdgcn_mfma_f32_16x16x32_f16(a1, b0, acc[1][0], 0, 0, 0);
          acc[1][1] = __builtin_amdgcn_mfma_f32_16x16x32_f16(a1, b1, acc[1][1], 0, 0, 0);
          acc[1][2] = __builtin_amdgcn_mfma_f32_16x16x32_f16(a1, b2, acc[1][2], 0, 0, 0);
          acc[1][3] = __builtin_amdgcn_mfma_f32_16x16x32_f16(a1, b3, acc[1][3], 0, 0, 0);
        }

        // Proven epilogue shape: all four gates lane-local, no exchange.
#pragma unroll
        for (int mf = 0; mf < 2; ++mf) {
#pragma unroll
          for (int r = 0; r < 4; ++r) {
            int b = 32 * w + 16 * mf + 4 * lhi + r;
            float gi = acc[mf][0][r] + bi;
            float gf = acc[mf][1][r] + bf;
            float gg = acc[mf][2][r] + bg;
            float go = acc[mf][3][r] + bo;
            float cn = sigm(gf) * cst[mf * 4 + r] + sigm(gi) * tanh_(gg);
            float hn = sigm(go) * tanh_(cn);
            cst[mf * 4 + r] = cn;
            if (l15 < 8) Hw[(size_t)b * 2048 + 1024 + j * 8 + l15] = (f16)hn;
            float v = hn * wl;  // wl == 0 on pad lanes
            v += __shfl_xor(v, 1);
            v += __shfl_xor(v, 2);
            v += __shfl_xor(v, 4);
            v += __shfl_xor(v, 8);
            if (l15 == 0)
              yp[(size_t)(i - 2) * NBAT * NL1 + b * NL1 + j] = v;
          }
        }
      }
    }

    // ---- step barrier: arrivals per-XCD; elected flusher per XCD pushes its
    //      L2 to the LLC (wbl2 sc1); one global spin. NO invalidates anywhere:
    //      consumers read h via agent-scope atomic loads (bypass L1/L2). ----
    if (i <= SEQ) {
      vm0();            // this wave's stores are in the local L2
      __syncthreads();  // whole block done
      if (tid == 0) {
        int old = __hip_atomic_fetch_add(&sy[SY_BARAX + 32 * xcd], 1, __ATOMIC_RELAXED,
                                         __HIP_MEMORY_SCOPE_AGENT);
        if (old == cx * i - 1) {  // last arriver on this XCD, step i
          asm volatile("buffer_wbl2 sc1\n\ts_waitcnt vmcnt(0)" ::: "memory");
          __hip_atomic_fetch_add(&sy[SY_BARG], 1, __ATOMIC_RELAXED,
                                 __HIP_MEMORY_SCOPE_AGENT);
        }
        spin_until(&sy[SY_BARG], nx * i);  // all XCDs flushed + arrived
      }
      __syncthreads();
    }
  }
}

__global__ __launch_bounds__(256) void zero_ws(f16* Hcat, int* sy) {
  int g = blockIdx.x * 256 + threadIdx.x, gs = gridDim.x * 256;
  for (int idx = g; idx < 2 * NBAT * 2048; idx += gs) Hcat[idx] = (f16)0.f;
  for (int idx = g; idx < 1024; idx += gs) sy[idx] = 0;
}

__global__ __launch_bounds__(256) void final_kernel(const float* __restrict__ yp,
                                                    const float* __restrict__ blin,
                                                    float* __restrict__ out) {
  const int idx = blockIdx.x * blockDim.x + threadIdx.x;  // 0..32767
  const int t = idx >> 7, b = idx & 127;
  const float* p = yp + ((size_t)t * NBAT + b) * NL1;
  float s = 0.f;
#pragma unroll
  for (int q = 0; q < NL1; ++q) s += p[q];
  out[b * SEQ + t] = s + blin[0];
}

extern "C" void kernel_launch(void* const* d_in, const int* in_sizes, int n_in,
                              void* d_out, int out_size, void* d_ws, size_t ws_size,
                              hipStream_t stream) {
  const float* X = (const float*)d_in[0];
  const float* Wih0 = (const float*)d_in[1];
  const float* Whh0 = (const float*)d_in[2];
  const float* bih0 = (const float*)d_in[3];
  const float* bhh0 = (const float*)d_in[4];
  const float* Wih1 = (const float*)d_in[5];
  const float* Whh1 = (const float*)d_in[6];
  const float* bih1 = (const float*)d_in[7];
  const float* bhh1 = (const float*)d_in[8];
  const float* Wlin = (const float*)d_in[9];
  const float* blin = (const float*)d_in[10];
  float* out = (float*)d_out;

  char* p = (char*)d_ws;
  f16* Hcat = (f16*)p;    p += (size_t)2 * NBAT * 2048 * 2;      // 1 MB
  float* yp = (float*)p;  p += (size_t)SEQ * NBAT * NL1 * 4;     // 16.8 MB
  int* sy = (int*)p;      p += 1024 * 4;

  hipFuncSetAttribute((const void*)lstm_persist,
                      hipFuncAttributeMaxDynamicSharedMemorySize, LDS_TOTAL);

  zero_ws<<<256, 256, 0, stream>>>(Hcat, sy);

  lstm_persist<<<NBLK, 256, LDS_TOTAL, stream>>>(
      X, Wih0, Whh0, bih0, bhh0, Wih1, Whh1, bih1, bhh1, Wlin,
      Hcat, yp, sy);

  final_kernel<<<NBAT, 256, 0, stream>>>(yp, blin, out);
}

// Round 14
// 4890.048 us; speedup vs baseline: 1.7563x; 1.7563x over previous
//
#include <hip/hip_runtime.h>
#include <stdint.h>

typedef _Float16 f16;
typedef f16 half8 __attribute__((ext_vector_type(8)));
typedef float f32x4 __attribute__((ext_vector_type(4)));
typedef unsigned long long u64;

constexpr int HID = 1024;
constexpr int NBAT = 128;
constexpr int SEQ = 256;
constexpr int NL0 = 64;          // layer0 blocks: 16 units, K=1024
constexpr int NL1 = 128;         // layer1 blocks: 8 units,  K=2048 ([Wih1|Whh1])
constexpr int NBLK = NL0 + NL1;  // 192
constexpr int HROWB = 4096;      // slot row bytes: [h0(1024) | h1(1024)] f16
constexpr int NSLOT = 258;       // rotating h slots (virgin addresses each step)
constexpr size_t SLOTE = (size_t)NBAT * 2048;  // f16 elems per slot
constexpr int WROWB0 = 2064;     // L0 LDS W row: 2048B + 16 pad
constexpr int WROWB1 = 4112;     // L1 LDS W row: 4096B + 16 pad
constexpr int ZOFF = 32 * WROWB1;    // 131584: start of shared zero band (L1)
constexpr int ZBYTES = 4160;         // covers ck*64 + lhi*16 (<= 4080) + slack
constexpr int WLDS = ZOFF + ZBYTES;  // 135744 >= 64*WROWB0 (132096)
constexpr int LDS_TOTAL = WLDS + 4096;  // + per-wave h-repack bounce (4 x 1KB)

// sync buffer layout (ints; 128B line separation)
constexpr int SY_INIT = 0;          // one-time init barrier
constexpr int SY_BARG = 32;         // global arrival counter (accumulating)
constexpr int SY_CNT = 64;          // +32*x: blocks on XCD x
constexpr int SY_BARAX = 64 + 256;  // +32*x: per-XCD arrivals (accumulating)

__device__ __forceinline__ float sigm(float x) { return 1.0f / (1.0f + __expf(-x)); }
__device__ __forceinline__ float tanh_(float x) {
  float e = __expf(2.0f * x);
  return (e - 1.0f) / (e + 1.0f);
}
__device__ __forceinline__ void vm0() {
  asm volatile("s_waitcnt vmcnt(0)" ::: "memory");
}
// h push: agent-scope atomic exchange executes at the LLC (coherence point) —
// the op class proven coherent by every barrier/flag in rounds 2-13.
__device__ __forceinline__ void push8(void* dst, u64 v) {
  (void)__hip_atomic_exchange((u64*)dst, v, __ATOMIC_RELAXED, __HIP_MEMORY_SCOPE_AGENT);
}
__device__ __forceinline__ void spin_until(int* p, int target) {
  uint64_t t0 = __builtin_amdgcn_s_memtime();
  while (__hip_atomic_load(p, __ATOMIC_RELAXED, __HIP_MEMORY_SCOPE_AGENT) < target) {
    __builtin_amdgcn_s_sleep(1);
    if (__builtin_amdgcn_s_memtime() - t0 > (1ULL << 29)) break;  // bounded on pathology
  }
}

__global__ __launch_bounds__(256, 1) void lstm_persist(
    const float* __restrict__ X,
    const float* __restrict__ Wih0, const float* __restrict__ Whh0,
    const float* __restrict__ bih0, const float* __restrict__ bhh0,
    const float* __restrict__ Wih1, const float* __restrict__ Whh1,
    const float* __restrict__ bih1, const float* __restrict__ bhh1,
    const float* __restrict__ Wlin,
    f16* __restrict__ Hbuf,   // [NSLOT][128][2048]  rotating slots
    float* __restrict__ yp,   // [256][128][128] per-L1-block y partials
    int* __restrict__ sy) {
  extern __shared__ char smem[];
  char* Wl = smem;
  char* Pk = smem + WLDS;   // per-wave h repack bounce (w*1024)

  const int bid = blockIdx.x, tid = threadIdx.x;
  const bool isL0 = bid < NL0;
  const int j = isL0 ? bid : bid - NL0;
  const int w = tid >> 6, l = tid & 63;
  const int l15 = l & 15, lhi = l >> 4;

  int xcd;
  asm volatile("s_getreg_b32 %0, hwreg(HW_REG_XCC_ID)" : "=s"(xcd));
  xcd &= 7;

  // ---- one-time W preload: f32 global -> f16 LDS (padded rows) ----
  if (isL0) {
    for (int it = 0; it < 256; ++it) {
      int e = it * 256 + tid;
      int r = e >> 10, k = e & 1023;                 // LDS row r = gate*16 + u
      int grow = (r >> 4) * HID + j * 16 + (r & 15);
      *(f16*)(Wl + r * WROWB0 + 2 * k) = (f16)Whh0[(size_t)grow * HID + k];
    }
  } else {
    for (int it = 0; it < 256; ++it) {
      int e = it * 256 + tid;
      int r = e >> 11, k = e & 2047;                 // LDS row r = gate*8 + u
      int grow = (r >> 3) * HID + j * 8 + (r & 7);
      float v = (k < 1024) ? Wih1[(size_t)grow * HID + k]
                           : Whh1[(size_t)grow * HID + (k - 1024)];
      *(f16*)(Wl + r * WROWB1 + 2 * k) = (f16)v;
    }
    for (int e = tid; e < ZBYTES / 2; e += 256)      // shared zero band (N-pad)
      *(f16*)(Wl + ZOFF + 2 * e) = (f16)0.f;
  }

  // ---- per-lane constants ----
  float bi, bf, bg, bo, wi_i = 0, wi_f = 0, wi_g = 0, wi_o = 0, wl = 0;
  if (isL0) {
    int m = j * 16 + l15;
    bi = bih0[m] + bhh0[m];
    bf = bih0[HID + m] + bhh0[HID + m];
    bg = bih0[2 * HID + m] + bhh0[2 * HID + m];
    bo = bih0[3 * HID + m] + bhh0[3 * HID + m];
    wi_i = Wih0[m]; wi_f = Wih0[HID + m];
    wi_g = Wih0[2 * HID + m]; wi_o = Wih0[3 * HID + m];
  } else {
    int u = j * 8 + (l15 & 7);
    bi = bih1[u] + bhh1[u];
    bf = bih1[HID + u] + bhh1[HID + u];
    bg = bih1[2 * HID + u] + bhh1[2 * HID + u];
    bo = bih1[3 * HID + u] + bhh1[3 * HID + u];
    wl = (l15 < 8) ? Wlin[u] : 0.f;  // pad lanes contribute 0 to y
  }
  float cst[8];
#pragma unroll
  for (int q = 0; q < 8; ++q) cst[q] = 0.f;

  // ---- init: learn per-XCD block count cx and XCD count nx (one-time) ----
  int cx = 0, nx = 0;
  if (tid == 0) {
    __hip_atomic_fetch_add(&sy[SY_CNT + 32 * xcd], 1, __ATOMIC_RELAXED,
                           __HIP_MEMORY_SCOPE_AGENT);
    __hip_atomic_fetch_add(&sy[SY_INIT], 1, __ATOMIC_RELAXED, __HIP_MEMORY_SCOPE_AGENT);
    spin_until(&sy[SY_INIT], NBLK);
    cx = __hip_atomic_load(&sy[SY_CNT + 32 * xcd], __ATOMIC_RELAXED,
                           __HIP_MEMORY_SCOPE_AGENT);
#pragma unroll
    for (int x = 0; x < 8; ++x)
      nx += (__hip_atomic_load(&sy[SY_CNT + 32 * x], __ATOMIC_RELAXED,
                               __HIP_MEMORY_SCOPE_AGENT) > 0);
  }
  __syncthreads();

  // L0 B pointers: proven 16-unit layout (b tiles at +16/32/48 rows)
  const char* Wb = Wl + l15 * WROWB0 + lhi * 16;
  // L1 B pointers: one per gate; cols 8-15 -> shared zero band (B-frag = 0)
  const char* Wg0 = Wl + ((l15 < 8) ? (0 * 8 + l15) * WROWB1 : ZOFF) + lhi * 16;
  const char* Wg1 = Wl + ((l15 < 8) ? (1 * 8 + l15) * WROWB1 : ZOFF) + lhi * 16;
  const char* Wg2 = Wl + ((l15 < 8) ? (2 * 8 + l15) * WROWB1 : ZOFF) + lhi * 16;
  const char* Wg3 = Wl + ((l15 < 8) ? (3 * 8 + l15) * WROWB1 : ZOFF) + lhi * 16;

  for (int i = 1; i <= SEQ + 1; ++i) {
    const bool active = isL0 ? (i <= SEQ) : (i >= 2);
    if (active) {
      // reads: slot i-1 (written last iter); writes: slot i (virgin addresses)
      const char* Asrc = (const char*)(Hbuf + (size_t)(i - 1) * SLOTE);
      char* Hw = (char*)(Hbuf + (size_t)i * SLOTE);
      const char* a0p = Asrc + (size_t)(32 * w + l15) * HROWB + lhi * 16;
      const char* a1p = a0p + (size_t)16 * HROWB;

      if (isL0) {
        // -------- layer0: 0-idx step i-1, K=1024 (h0 half), 4 gate-tiles --------
        float xr[8];
#pragma unroll
        for (int mf = 0; mf < 2; ++mf)
#pragma unroll
          for (int r = 0; r < 4; ++r)
            xr[mf * 4 + r] = X[(32 * w + 16 * mf + 4 * lhi + r) * SEQ + (i - 1)];

        half8 pa[8], pb[8];
#pragma unroll
        for (int k0 = 0; k0 < 8; ++k0) {
          pa[k0] = *(const half8*)(a0p + k0 * 64);
          pb[k0] = *(const half8*)(a1p + k0 * 64);
        }
        f32x4 acc[2][4];
#pragma unroll
        for (int mf = 0; mf < 2; ++mf)
#pragma unroll
          for (int n = 0; n < 4; ++n) acc[mf][n] = f32x4{0.f, 0.f, 0.f, 0.f};

#pragma unroll
        for (int ck = 0; ck < 32; ++ck) {
          half8 a0 = pa[ck & 7], a1 = pb[ck & 7];
          if (ck < 24) {
            pa[ck & 7] = *(const half8*)(a0p + (ck + 8) * 64);
            pb[ck & 7] = *(const half8*)(a1p + (ck + 8) * 64);
          }
          half8 b0 = *(const half8*)(Wb + ck * 64);
          half8 b1 = *(const half8*)(Wb + 16 * WROWB0 + ck * 64);
          half8 b2 = *(const half8*)(Wb + 32 * WROWB0 + ck * 64);
          half8 b3 = *(const half8*)(Wb + 48 * WROWB0 + ck * 64);
          acc[0][0] = __builtin_amdgcn_mfma_f32_16x16x32_f16(a0, b0, acc[0][0], 0, 0, 0);
          acc[0][1] = __builtin_amdgcn_mfma_f32_16x16x32_f16(a0, b1, acc[0][1], 0, 0, 0);
          acc[0][2] = __builtin_amdgcn_mfma_f32_16x16x32_f16(a0, b2, acc[0][2], 0, 0, 0);
          acc[0][3] = __builtin_amdgcn_mfma_f32_16x16x32_f16(a0, b3, acc[0][3], 0, 0, 0);
          acc[1][0] = __builtin_amdgcn_mfma_f32_16x16x32_f16(a1, b0, acc[1][0], 0, 0, 0);
          acc[1][1] = __builtin_amdgcn_mfma_f32_16x16x32_f16(a1, b1, acc[1][1], 0, 0, 0);
          acc[1][2] = __builtin_amdgcn_mfma_f32_16x16x32_f16(a1, b2, acc[1][2], 0, 0, 0);
          acc[1][3] = __builtin_amdgcn_mfma_f32_16x16x32_f16(a1, b3, acc[1][3], 0, 0, 0);
        }

        // cell update -> per-wave LDS bounce [32 rows][16 cols] f16 (1KB)
#pragma unroll
        for (int mf = 0; mf < 2; ++mf) {
#pragma unroll
          for (int r = 0; r < 4; ++r) {
            float xv = xr[mf * 4 + r];
            float gi = acc[mf][0][r] + bi + xv * wi_i;
            float gf = acc[mf][1][r] + bf + xv * wi_f;
            float gg = acc[mf][2][r] + bg + xv * wi_g;
            float go = acc[mf][3][r] + bo + xv * wi_o;
            float cn = sigm(gf) * cst[mf * 4 + r] + sigm(gi) * tanh_(gg);
            float hn = sigm(go) * tanh_(cn);
            cst[mf * 4 + r] = cn;
            // row = local batch (16*mf+4*lhi+r), col = l15
            *(f16*)(Pk + w * 1024 + (16 * mf + 4 * lhi + r) * 32 + l15 * 2) = (f16)hn;
          }
        }
        asm volatile("s_waitcnt lgkmcnt(0)" ::: "memory");  // wave-local LDS done
        {
          // lane l re-reads 16B: row l>>1, byte half (l&1)*16 -> 2 x 8B swaps
          const char* src = Pk + w * 1024 + (l >> 1) * 32 + (l & 1) * 16;
          u64 v0 = *(const u64*)src;
          u64 v1 = *(const u64*)(src + 8);
          char* dst = Hw + (size_t)(32 * w + (l >> 1)) * HROWB + j * 32 + (l & 1) * 16;
          push8(dst, v0);
          push8(dst + 8, v1);
        }
      } else {
        // ---- layer1: 0-idx step i-2, K=2048 full [h0|h1] row, 4 gate-tiles ----
        half8 pa[8], pb[8];
#pragma unroll
        for (int k0 = 0; k0 < 8; ++k0) {
          pa[k0] = *(const half8*)(a0p + k0 * 64);
          pb[k0] = *(const half8*)(a1p + k0 * 64);
        }
        f32x4 acc[2][4];
#pragma unroll
        for (int mf = 0; mf < 2; ++mf)
#pragma unroll
          for (int n = 0; n < 4; ++n) acc[mf][n] = f32x4{0.f, 0.f, 0.f, 0.f};

#pragma unroll
        for (int ck = 0; ck < 64; ++ck) {
          half8 a0 = pa[ck & 7], a1 = pb[ck & 7];
          if (ck < 56) {
            pa[ck & 7] = *(const half8*)(a0p + (ck + 8) * 64);
            pb[ck & 7] = *(const half8*)(a1p + (ck + 8) * 64);
          }
          half8 b0 = *(const half8*)(Wg0 + ck * 64);
          half8 b1 = *(const half8*)(Wg1 + ck * 64);
          half8 b2 = *(const half8*)(Wg2 + ck * 64);
          half8 b3 = *(const half8*)(Wg3 + ck * 64);
          acc[0][0] = __builtin_amdgcn_mfma_f32_16x16x32_f16(a0, b0, acc[0][0], 0, 0, 0);
          acc[0][1] = __builtin_amdgcn_mfma_f32_16x16x32_f16(a0, b1, acc[0][1], 0, 0, 0);
          acc[0][2] = __builtin_amdgcn_mfma_f32_16x16x32_f16(a0, b2, acc[0][2], 0, 0, 0);
          acc[0][3] = __builtin_amdgcn_mfma_f32_16x16x32_f16(a0, b3, acc[0][3], 0, 0, 0);
          acc[1][0] = __builtin_amdgcn_mfma_f32_16x16x32_f16(a1, b0, acc[1][0], 0, 0, 0);
          acc[1][1] = __builtin_amdgcn_mfma_f32_16x16x32_f16(a1, b1, acc[1][1], 0, 0, 0);
          acc[1][2] = __builtin_amdgcn_mfma_f32_16x16x32_f16(a1, b2, acc[1][2], 0, 0, 0);
          acc[1][3] = __builtin_amdgcn_mfma_f32_16x16x32_f16(a1, b3, acc[1][3], 0, 0, 0);
        }

        // Proven epilogue shape: all four gates lane-local, no exchange.
        // h -> per-wave LDS bounce [32 rows][8 cols] f16 (512B)
#pragma unroll
        for (int mf = 0; mf < 2; ++mf) {
#pragma unroll
          for (int r = 0; r < 4; ++r) {
            int b = 32 * w + 16 * mf + 4 * lhi + r;
            float gi = acc[mf][0][r] + bi;
            float gf = acc[mf][1][r] + bf;
            float gg = acc[mf][2][r] + bg;
            float go = acc[mf][3][r] + bo;
            float cn = sigm(gf) * cst[mf * 4 + r] + sigm(gi) * tanh_(gg);
            float hn = sigm(go) * tanh_(cn);
            cst[mf * 4 + r] = cn;
            if (l15 < 8)
              *(f16*)(Pk + w * 512 + (16 * mf + 4 * lhi + r) * 16 + l15 * 2) = (f16)hn;
            float v = hn * wl;  // wl == 0 on pad lanes
            v += __shfl_xor(v, 1);
            v += __shfl_xor(v, 2);
            v += __shfl_xor(v, 4);
            v += __shfl_xor(v, 8);
            if (l15 == 0)
              yp[(size_t)(i - 2) * NBAT * NL1 + b * NL1 + j] = v;
          }
        }
        asm volatile("s_waitcnt lgkmcnt(0)" ::: "memory");  // wave-local LDS done
        {
          // lane l re-reads 8B: row l>>1, half (l&1) -> 1 x 8B swap
          u64 v = *(const u64*)(Pk + w * 512 + (l >> 1) * 16 + (l & 1) * 8);
          char* dst =
              Hw + (size_t)(32 * w + (l >> 1)) * HROWB + 2048 + j * 16 + (l & 1) * 8;
          push8(dst, v);
        }
      }
    }

    // ---- step barrier: pure arithmetic, no cache maintenance.
    //      h is at the LLC via atomic swaps; consumers read virgin addresses. ----
    if (i <= SEQ) {
      vm0();            // swaps acknowledged by the LLC
      __syncthreads();  // whole block done
      if (tid == 0) {
        int old = __hip_atomic_fetch_add(&sy[SY_BARAX + 32 * xcd], 1, __ATOMIC_RELAXED,
                                         __HIP_MEMORY_SCOPE_AGENT);
        if (old == cx * i - 1)  // last arriver on this XCD, step i
          __hip_atomic_fetch_add(&sy[SY_BARG], 1, __ATOMIC_RELAXED,
                                 __HIP_MEMORY_SCOPE_AGENT);
        spin_until(&sy[SY_BARG], nx * i);  // all blocks arrived chip-wide
      }
      __syncthreads();
    }
  }
}

__global__ __launch_bounds__(256) void zero_ws(f16* Hbuf, int* sy) {
  int g = blockIdx.x * 256 + threadIdx.x, gs = gridDim.x * 256;
  // zero slots 0 (read at iter 1) and 1 (h1 half read at iter 2)
  for (size_t idx = g; idx < 2 * SLOTE; idx += gs) Hbuf[idx] = (f16)0.f;
  for (int idx = g; idx < 1024; idx += gs) sy[idx] = 0;
}

__global__ __launch_bounds__(256) void final_kernel(const float* __restrict__ yp,
                                                    const float* __restrict__ blin,
                                                    float* __restrict__ out) {
  const int idx = blockIdx.x * blockDim.x + threadIdx.x;  // 0..32767
  const int t = idx >> 7, b = idx & 127;
  const float* p = yp + ((size_t)t * NBAT + b) * NL1;
  float s = 0.f;
#pragma unroll
  for (int q = 0; q < NL1; ++q) s += p[q];
  out[b * SEQ + t] = s + blin[0];
}

extern "C" void kernel_launch(void* const* d_in, const int* in_sizes, int n_in,
                              void* d_out, int out_size, void* d_ws, size_t ws_size,
                              hipStream_t stream) {
  const float* X = (const float*)d_in[0];
  const float* Wih0 = (const float*)d_in[1];
  const float* Whh0 = (const float*)d_in[2];
  const float* bih0 = (const float*)d_in[3];
  const float* bhh0 = (const float*)d_in[4];
  const float* Wih1 = (const float*)d_in[5];
  const float* Whh1 = (const float*)d_in[6];
  const float* bih1 = (const float*)d_in[7];
  const float* bhh1 = (const float*)d_in[8];
  const float* Wlin = (const float*)d_in[9];
  const float* blin = (const float*)d_in[10];
  float* out = (float*)d_out;

  char* p = (char*)d_ws;
  f16* Hbuf = (f16*)p;    p += (size_t)NSLOT * SLOTE * 2;        // 132 MB
  float* yp = (float*)p;  p += (size_t)SEQ * NBAT * NL1 * 4;     // 16.8 MB
  int* sy = (int*)p;      p += 1024 * 4;

  hipFuncSetAttribute((const void*)lstm_persist,
                      hipFuncAttributeMaxDynamicSharedMemorySize, LDS_TOTAL);

  zero_ws<<<256, 256, 0, stream>>>(Hbuf, sy);

  lstm_persist<<<NBLK, 256, LDS_TOTAL, stream>>>(
      X, Wih0, Whh0, bih0, bhh0, Wih1, Whh1, bih1, bhh1, Wlin,
      Hbuf, yp, sy);

  final_kernel<<<NBAT, 256, 0, stream>>>(yp, blin, out);
}

// Round 15
// 4735.135 us; speedup vs baseline: 1.8138x; 1.0327x over previous
//
#include <hip/hip_runtime.h>
#include <stdint.h>

typedef _Float16 f16;
typedef f16 half8 __attribute__((ext_vector_type(8)));
typedef float f32x4 __attribute__((ext_vector_type(4)));
typedef unsigned long long u64;

constexpr int HID = 1024;
constexpr int NBAT = 128;
constexpr int SEQ = 256;
constexpr int NL0 = 64;          // layer0 blocks: 16 units, K=1024
constexpr int NL1 = 128;         // layer1 blocks: 8 units,  K=2048 ([Wih1|Whh1])
constexpr int NBLK = NL0 + NL1;  // 192
constexpr int HROWB = 4096;      // slot row bytes: [h0(1024) | h1(1024)] f16
constexpr int NSLOT = 258;       // rotating h slots (virgin addresses each step)
constexpr size_t SLOTE = (size_t)NBAT * 2048;  // f16 elems per slot
constexpr int WROWB0 = 2064;     // L0 LDS W row: 2048B + 16 pad
constexpr int WROWB1 = 4112;     // L1 LDS W row: 4096B + 16 pad
constexpr int ZOFF = 32 * WROWB1;    // 131584: start of shared zero band (L1)
constexpr int ZBYTES = 4160;         // covers ck*64 + lhi*16 (<= 4080) + slack
constexpr int WLDS = ZOFF + ZBYTES;  // 135744 >= 64*WROWB0 (132096)
constexpr int LDS_TOTAL = WLDS + 4096;  // + per-wave h-repack bounce (8 x 512B)

// sync buffer layout (ints; 128B line separation)
constexpr int SY_INIT = 0;           // one-time init barrier
constexpr int SY_BG0 = 32;           // global L0 XCD-completion counter
constexpr int SY_BG1 = 64;           // global L1 XCD-completion counter
constexpr int SY_CNT0 = 96;          // +32*x: L0 blocks on XCD x
constexpr int SY_CNT1 = 96 + 256;    // +32*x: L1 blocks on XCD x
constexpr int SY_BARX0 = 96 + 512;   // +32*x: per-XCD L0 arrivals (accumulating)
constexpr int SY_BARX1 = 96 + 768;   // +32*x: per-XCD L1 arrivals (accumulating)

__device__ __forceinline__ float sigm(float x) { return 1.0f / (1.0f + __expf(-x)); }
__device__ __forceinline__ float tanh_(float x) {
  float e = __expf(2.0f * x);
  return (e - 1.0f) / (e + 1.0f);
}
__device__ __forceinline__ void vm0() {
  asm volatile("s_waitcnt vmcnt(0)" ::: "memory");
}
// h push: agent-scope atomic exchange executes at the LLC (coherence point) —
// the op class proven coherent by every barrier/flag in rounds 2-14.
__device__ __forceinline__ void push8(void* dst, u64 v) {
  (void)__hip_atomic_exchange((u64*)dst, v, __ATOMIC_RELAXED, __HIP_MEMORY_SCOPE_AGENT);
}
__device__ __forceinline__ void spin_until(int* p, int target) {
  uint64_t t0 = __builtin_amdgcn_s_memtime();
  while (__hip_atomic_load(p, __ATOMIC_RELAXED, __HIP_MEMORY_SCOPE_AGENT) < target) {
    __builtin_amdgcn_s_sleep(1);
    if (__builtin_amdgcn_s_memtime() - t0 > (1ULL << 29)) break;  // bounded on pathology
  }
}

// 512 threads = 8 waves (2/SIMD for TLP); each wave owns ONE 16-row m-frag.
__global__ __launch_bounds__(512, 1) void lstm_persist(
    const float* __restrict__ X,
    const float* __restrict__ Wih0, const float* __restrict__ Whh0,
    const float* __restrict__ bih0, const float* __restrict__ bhh0,
    const float* __restrict__ Wih1, const float* __restrict__ Whh1,
    const float* __restrict__ bih1, const float* __restrict__ bhh1,
    const float* __restrict__ Wlin,
    f16* __restrict__ Hbuf,   // [NSLOT][128][2048]  rotating slots
    float* __restrict__ yp,   // [256][128][128] per-L1-block y partials
    int* __restrict__ sy) {
  extern __shared__ char smem[];
  char* Wl = smem;
  char* Pk = smem + WLDS;   // per-wave h repack bounce (w*512)

  const int bid = blockIdx.x, tid = threadIdx.x;
  const bool isL0 = bid < NL0;
  const int j = isL0 ? bid : bid - NL0;
  const int w = tid >> 6, l = tid & 63;
  const int l15 = l & 15, lhi = l >> 4;

  int xcd;
  asm volatile("s_getreg_b32 %0, hwreg(HW_REG_XCC_ID)" : "=s"(xcd));
  xcd &= 7;

  // ---- one-time W preload: f32 global -> f16 LDS (padded rows) ----
  if (isL0) {
    for (int it = 0; it < 128; ++it) {
      int e = it * 512 + tid;
      int r = e >> 10, k = e & 1023;                 // LDS row r = gate*16 + u
      int grow = (r >> 4) * HID + j * 16 + (r & 15);
      *(f16*)(Wl + r * WROWB0 + 2 * k) = (f16)Whh0[(size_t)grow * HID + k];
    }
  } else {
    for (int it = 0; it < 128; ++it) {
      int e = it * 512 + tid;
      int r = e >> 11, k = e & 2047;                 // LDS row r = gate*8 + u
      int grow = (r >> 3) * HID + j * 8 + (r & 7);
      float v = (k < 1024) ? Wih1[(size_t)grow * HID + k]
                           : Whh1[(size_t)grow * HID + (k - 1024)];
      *(f16*)(Wl + r * WROWB1 + 2 * k) = (f16)v;
    }
    for (int e = tid; e < ZBYTES / 2; e += 512)      // shared zero band (N-pad)
      *(f16*)(Wl + ZOFF + 2 * e) = (f16)0.f;
  }

  // ---- per-lane constants ----
  float bi, bf, bg, bo, wi_i = 0, wi_f = 0, wi_g = 0, wi_o = 0, wl = 0;
  if (isL0) {
    int m = j * 16 + l15;
    bi = bih0[m] + bhh0[m];
    bf = bih0[HID + m] + bhh0[HID + m];
    bg = bih0[2 * HID + m] + bhh0[2 * HID + m];
    bo = bih0[3 * HID + m] + bhh0[3 * HID + m];
    wi_i = Wih0[m]; wi_f = Wih0[HID + m];
    wi_g = Wih0[2 * HID + m]; wi_o = Wih0[3 * HID + m];
  } else {
    int u = j * 8 + (l15 & 7);
    bi = bih1[u] + bhh1[u];
    bf = bih1[HID + u] + bhh1[HID + u];
    bg = bih1[2 * HID + u] + bhh1[2 * HID + u];
    bo = bih1[3 * HID + u] + bhh1[3 * HID + u];
    wl = (l15 < 8) ? Wlin[u] : 0.f;  // pad lanes contribute 0 to y
  }
  float cst[4];
#pragma unroll
  for (int q = 0; q < 4; ++q) cst[q] = 0.f;

  // ---- init: per-XCD per-layer block counts; nx0/nx1 = #XCDs present ----
  int cxm = 0, nx0 = 0, nx1 = 0;
  if (tid == 0) {
    __hip_atomic_fetch_add(&sy[(isL0 ? SY_CNT0 : SY_CNT1) + 32 * xcd], 1,
                           __ATOMIC_RELAXED, __HIP_MEMORY_SCOPE_AGENT);
    __hip_atomic_fetch_add(&sy[SY_INIT], 1, __ATOMIC_RELAXED, __HIP_MEMORY_SCOPE_AGENT);
    spin_until(&sy[SY_INIT], NBLK);
    cxm = __hip_atomic_load(&sy[(isL0 ? SY_CNT0 : SY_CNT1) + 32 * xcd],
                            __ATOMIC_RELAXED, __HIP_MEMORY_SCOPE_AGENT);
#pragma unroll
    for (int x = 0; x < 8; ++x) {
      nx0 += (__hip_atomic_load(&sy[SY_CNT0 + 32 * x], __ATOMIC_RELAXED,
                                __HIP_MEMORY_SCOPE_AGENT) > 0);
      nx1 += (__hip_atomic_load(&sy[SY_CNT1 + 32 * x], __ATOMIC_RELAXED,
                                __HIP_MEMORY_SCOPE_AGENT) > 0);
    }
  }
  __syncthreads();

  // L0 B pointers: proven 16-unit layout (b tiles at +16/32/48 rows)
  const char* Wb = Wl + l15 * WROWB0 + lhi * 16;
  // L1 B pointers: one per gate; cols 8-15 -> shared zero band (B-frag = 0)
  const char* Wg0 = Wl + ((l15 < 8) ? (0 * 8 + l15) * WROWB1 : ZOFF) + lhi * 16;
  const char* Wg1 = Wl + ((l15 < 8) ? (1 * 8 + l15) * WROWB1 : ZOFF) + lhi * 16;
  const char* Wg2 = Wl + ((l15 < 8) ? (2 * 8 + l15) * WROWB1 : ZOFF) + lhi * 16;
  const char* Wg3 = Wl + ((l15 < 8) ? (3 * 8 + l15) * WROWB1 : ZOFF) + lhi * 16;

  for (int i = 1; i <= SEQ + 1; ++i) {
    // ---- layer-split waits (top of iter): L0 needs only L0(i-1);
    //      L1 needs L0(i-1) and L1(i-1). Counters accumulate. ----
    if (i >= 2) {
      if (tid == 0) {
        spin_until(&sy[SY_BG0], nx0 * (i - 1));
        if (!isL0) spin_until(&sy[SY_BG1], nx1 * (i - 1));
      }
      __syncthreads();
    }

    const bool active = isL0 ? (i <= SEQ) : (i >= 2);
    if (active) {
      // reads: slot i-1 (written last iter); writes: slot i (virgin addresses)
      const char* Asrc = (const char*)(Hbuf + (size_t)(i - 1) * SLOTE);
      char* Hw = (char*)(Hbuf + (size_t)i * SLOTE);
      const char* a0p = Asrc + (size_t)(16 * w + l15) * HROWB + lhi * 16;

      if (isL0) {
        // ----- layer0: 0-idx step i-1, K=1024 (h0 half), 4 gate-tiles -----
        float xr[4];
#pragma unroll
        for (int r = 0; r < 4; ++r)
          xr[r] = X[(16 * w + 4 * lhi + r) * SEQ + (i - 1)];

        half8 pa[8];
#pragma unroll
        for (int k0 = 0; k0 < 8; ++k0) pa[k0] = *(const half8*)(a0p + k0 * 64);
        f32x4 acc[4];
#pragma unroll
        for (int n = 0; n < 4; ++n) acc[n] = f32x4{0.f, 0.f, 0.f, 0.f};

#pragma unroll
        for (int ck = 0; ck < 32; ++ck) {
          half8 a0 = pa[ck & 7];
          if (ck < 24) pa[ck & 7] = *(const half8*)(a0p + (ck + 8) * 64);
          half8 b0 = *(const half8*)(Wb + ck * 64);
          half8 b1 = *(const half8*)(Wb + 16 * WROWB0 + ck * 64);
          half8 b2 = *(const half8*)(Wb + 32 * WROWB0 + ck * 64);
          half8 b3 = *(const half8*)(Wb + 48 * WROWB0 + ck * 64);
          acc[0] = __builtin_amdgcn_mfma_f32_16x16x32_f16(a0, b0, acc[0], 0, 0, 0);
          acc[1] = __builtin_amdgcn_mfma_f32_16x16x32_f16(a0, b1, acc[1], 0, 0, 0);
          acc[2] = __builtin_amdgcn_mfma_f32_16x16x32_f16(a0, b2, acc[2], 0, 0, 0);
          acc[3] = __builtin_amdgcn_mfma_f32_16x16x32_f16(a0, b3, acc[3], 0, 0, 0);
        }

        // cell update -> per-wave LDS bounce [16 rows][16 cols] f16 (512B)
#pragma unroll
        for (int r = 0; r < 4; ++r) {
          float xv = xr[r];
          float gi = acc[0][r] + bi + xv * wi_i;
          float gf = acc[1][r] + bf + xv * wi_f;
          float gg = acc[2][r] + bg + xv * wi_g;
          float go = acc[3][r] + bo + xv * wi_o;
          float cn = sigm(gf) * cst[r] + sigm(gi) * tanh_(gg);
          float hn = sigm(go) * tanh_(cn);
          cst[r] = cn;
          *(f16*)(Pk + w * 512 + (4 * lhi + r) * 32 + l15 * 2) = (f16)hn;
        }
        asm volatile("s_waitcnt lgkmcnt(0)" ::: "memory");  // wave-local LDS done
        {
          // lane l pushes 8B: row l>>2, quarter l&3
          u64 v = *(const u64*)(Pk + w * 512 + (l >> 2) * 32 + (l & 3) * 8);
          char* dst = Hw + (size_t)(16 * w + (l >> 2)) * HROWB + j * 32 + (l & 3) * 8;
          push8(dst, v);
        }
      } else {
        // ----- layer1: 0-idx step i-2, K=2048 full [h0|h1] row, 4 gate-tiles -----
        half8 pa[16];
#pragma unroll
        for (int k0 = 0; k0 < 16; ++k0) pa[k0] = *(const half8*)(a0p + k0 * 64);
        f32x4 acc[4];
#pragma unroll
        for (int n = 0; n < 4; ++n) acc[n] = f32x4{0.f, 0.f, 0.f, 0.f};

#pragma unroll
        for (int ck = 0; ck < 64; ++ck) {
          half8 a0 = pa[ck & 15];
          if (ck < 48) pa[ck & 15] = *(const half8*)(a0p + (ck + 16) * 64);
          half8 b0 = *(const half8*)(Wg0 + ck * 64);
          half8 b1 = *(const half8*)(Wg1 + ck * 64);
          half8 b2 = *(const half8*)(Wg2 + ck * 64);
          half8 b3 = *(const half8*)(Wg3 + ck * 64);
          acc[0] = __builtin_amdgcn_mfma_f32_16x16x32_f16(a0, b0, acc[0], 0, 0, 0);
          acc[1] = __builtin_amdgcn_mfma_f32_16x16x32_f16(a0, b1, acc[1], 0, 0, 0);
          acc[2] = __builtin_amdgcn_mfma_f32_16x16x32_f16(a0, b2, acc[2], 0, 0, 0);
          acc[3] = __builtin_amdgcn_mfma_f32_16x16x32_f16(a0, b3, acc[3], 0, 0, 0);
        }

        // Proven epilogue: all four gates lane-local, no exchange.
#pragma unroll
        for (int r = 0; r < 4; ++r) {
          int b = 16 * w + 4 * lhi + r;
          float gi = acc[0][r] + bi;
          float gf = acc[1][r] + bf;
          float gg = acc[2][r] + bg;
          float go = acc[3][r] + bo;
          float cn = sigm(gf) * cst[r] + sigm(gi) * tanh_(gg);
          float hn = sigm(go) * tanh_(cn);
          cst[r] = cn;
          if (l15 < 8)
            *(f16*)(Pk + w * 512 + (4 * lhi + r) * 16 + l15 * 2) = (f16)hn;
          float v = hn * wl;  // wl == 0 on pad lanes
          v += __shfl_xor(v, 1);
          v += __shfl_xor(v, 2);
          v += __shfl_xor(v, 4);
          v += __shfl_xor(v, 8);
          if (l15 == 0)
            yp[(size_t)(i - 2) * NBAT * NL1 + b * NL1 + j] = v;
        }
        asm volatile("s_waitcnt lgkmcnt(0)" ::: "memory");  // wave-local LDS done
        if (l < 32) {
          // lane l pushes 8B: row l>>1, half l&1
          u64 v = *(const u64*)(Pk + w * 512 + (l >> 1) * 16 + (l & 1) * 8);
          char* dst =
              Hw + (size_t)(16 * w + (l >> 1)) * HROWB + 2048 + j * 16 + (l & 1) * 8;
          push8(dst, v);
        }
      }
    }

    // ---- arrival (end of iter): per-XCD per-layer line; last arriver bumps
    //      the layer's global counter. No spin here. ----
    if (i <= SEQ) {
      vm0();            // swaps acknowledged by the LLC
      __syncthreads();  // whole block done
      if (tid == 0) {
        int* ax = &sy[(isL0 ? SY_BARX0 : SY_BARX1) + 32 * xcd];
        int old = __hip_atomic_fetch_add(ax, 1, __ATOMIC_RELAXED,
                                         __HIP_MEMORY_SCOPE_AGENT);
        if (old == cxm * i - 1)
          __hip_atomic_fetch_add(&sy[isL0 ? SY_BG0 : SY_BG1], 1, __ATOMIC_RELAXED,
                                 __HIP_MEMORY_SCOPE_AGENT);
      }
    }
  }
}

__global__ __launch_bounds__(256) void zero_ws(f16* Hbuf, int* sy) {
  int g = blockIdx.x * 256 + threadIdx.x, gs = gridDim.x * 256;
  // zero slots 0 (read at iter 1) and 1 (h1 half read at iter 2)
  for (size_t idx = g; idx < 2 * SLOTE; idx += gs) Hbuf[idx] = (f16)0.f;
  for (int idx = g; idx < 2048; idx += gs) sy[idx] = 0;
}

__global__ __launch_bounds__(256) void final_kernel(const float* __restrict__ yp,
                                                    const float* __restrict__ blin,
                                                    float* __restrict__ out) {
  const int idx = blockIdx.x * blockDim.x + threadIdx.x;  // 0..32767
  const int t = idx >> 7, b = idx & 127;
  const float* p = yp + ((size_t)t * NBAT + b) * NL1;
  float s = 0.f;
#pragma unroll
  for (int q = 0; q < NL1; ++q) s += p[q];
  out[b * SEQ + t] = s + blin[0];
}

extern "C" void kernel_launch(void* const* d_in, const int* in_sizes, int n_in,
                              void* d_out, int out_size, void* d_ws, size_t ws_size,
                              hipStream_t stream) {
  const float* X = (const float*)d_in[0];
  const float* Wih0 = (const float*)d_in[1];
  const float* Whh0 = (const float*)d_in[2];
  const float* bih0 = (const float*)d_in[3];
  const float* bhh0 = (const float*)d_in[4];
  const float* Wih1 = (const float*)d_in[5];
  const float* Whh1 = (const float*)d_in[6];
  const float* bih1 = (const float*)d_in[7];
  const float* bhh1 = (const float*)d_in[8];
  const float* Wlin = (const float*)d_in[9];
  const float* blin = (const float*)d_in[10];
  float* out = (float*)d_out;

  char* p = (char*)d_ws;
  f16* Hbuf = (f16*)p;    p += (size_t)NSLOT * SLOTE * 2;        // 132 MB
  float* yp = (float*)p;  p += (size_t)SEQ * NBAT * NL1 * 4;     // 16.8 MB
  int* sy = (int*)p;      p += 2048 * 4;

  hipFuncSetAttribute((const void*)lstm_persist,
                      hipFuncAttributeMaxDynamicSharedMemorySize, LDS_TOTAL);

  zero_ws<<<256, 256, 0, stream>>>(Hbuf, sy);

  lstm_persist<<<NBLK, 512, LDS_TOTAL, stream>>>(
      X, Wih0, Whh0, bih0, bhh0, Wih1, Whh1, bih1, bhh1, Wlin,
      Hbuf, yp, sy);

  final_kernel<<<NBAT, 256, 0, stream>>>(yp, blin, out);
}

// Round 16
// 4708.410 us; speedup vs baseline: 1.8241x; 1.0057x over previous
//
#include <hip/hip_runtime.h>
#include <stdint.h>

typedef _Float16 f16;
typedef f16 half8 __attribute__((ext_vector_type(8)));
typedef float f32x4 __attribute__((ext_vector_type(4)));
typedef unsigned long long u64;

constexpr int HID = 1024;
constexpr int NBAT = 128;
constexpr int SEQ = 256;
constexpr int NL0 = 64;          // layer0 blocks: 16 units, K=1024
constexpr int NL1 = 128;         // layer1 blocks: 8 units,  K=2048 ([Wih1|Whh1])
constexpr int NBLK = NL0 + NL1;  // 192
constexpr int HROWB = 4096;      // slot row bytes: [h0(1024) | h1(1024)] f16
constexpr int NSLOT = 258;       // rotating h slots (virgin addresses each step)
constexpr size_t SLOTE = (size_t)NBAT * 2048;  // f16 elems per slot
constexpr int WROWB0 = 2064;     // L0 LDS W row: 2048B + 16 pad
constexpr int WROWB1 = 4112;     // L1 LDS W row: 4096B + 16 pad
constexpr int ZOFF = 32 * WROWB1;    // 131584: start of shared zero band (L1)
constexpr int ZBYTES = 4160;         // covers ck*64 + lhi*16 (<= 4080) + slack
constexpr int WLDS = ZOFF + ZBYTES;  // 135744 >= 64*WROWB0 (132096)
constexpr int LDS_TOTAL = WLDS + 4096;  // + per-wave h-repack bounce (8 x 512B)

// sync buffer layout (ints; 128B line separation).
// Poller-count discipline (anti poll-storm): BG <= 8 pollers (relays only);
// GO[x] <= ~23 pollers; arrival lines <= 24 adders.
constexpr int SY_INIT = 0;        // one-time init barrier
constexpr int SY_BG = 32;         // global "XCD complete" counter (accumulating)
constexpr int SY_CNTX = 64;       // +32*x: blocks on XCD x (init; also gives rank)
constexpr int SY_BARX = 320;      // +32*x: per-XCD arrivals (accumulating)
constexpr int SY_GO = 576;        // +32*x: per-XCD broadcast of completed iter

__device__ __forceinline__ float sigm(float x) { return 1.0f / (1.0f + __expf(-x)); }
__device__ __forceinline__ float tanh_(float x) {
  float e = __expf(2.0f * x);
  return (e - 1.0f) / (e + 1.0f);
}
__device__ __forceinline__ void vm0() {
  asm volatile("s_waitcnt vmcnt(0)" ::: "memory");
}
// h push: agent-scope atomic exchange executes at the LLC (coherence point) —
// the op class proven coherent by every barrier/flag in rounds 2-15.
__device__ __forceinline__ void push8(void* dst, u64 v) {
  (void)__hip_atomic_exchange((u64*)dst, v, __ATOMIC_RELAXED, __HIP_MEMORY_SCOPE_AGENT);
}
__device__ __forceinline__ void spin_until(int* p, int target) {
  uint64_t t0 = __builtin_amdgcn_s_memtime();
  while (__hip_atomic_load(p, __ATOMIC_RELAXED, __HIP_MEMORY_SCOPE_AGENT) < target) {
    __builtin_amdgcn_s_sleep(1);
    if (__builtin_amdgcn_s_memtime() - t0 > (1ULL << 29)) break;  // bounded on pathology
  }
}

// 512 threads = 8 waves (2/SIMD); each wave owns ONE 16-row m-frag.
__global__ __launch_bounds__(512, 1) void lstm_persist(
    const float* __restrict__ X,
    const float* __restrict__ Wih0, const float* __restrict__ Whh0,
    const float* __restrict__ bih0, const float* __restrict__ bhh0,
    const float* __restrict__ Wih1, const float* __restrict__ Whh1,
    const float* __restrict__ bih1, const float* __restrict__ bhh1,
    const float* __restrict__ Wlin,
    f16* __restrict__ Hbuf,   // [NSLOT][128][2048]  rotating slots
    float* __restrict__ yp,   // [256][128][128] per-L1-block y partials
    int* __restrict__ sy) {
  extern __shared__ char smem[];
  char* Wl = smem;
  char* Pk = smem + WLDS;   // per-wave h repack bounce (w*512)

  const int bid = blockIdx.x, tid = threadIdx.x;
  const bool isL0 = bid < NL0;
  const int j = isL0 ? bid : bid - NL0;
  const int w = tid >> 6, l = tid & 63;
  const int l15 = l & 15, lhi = l >> 4;

  int xcd;
  asm volatile("s_getreg_b32 %0, hwreg(HW_REG_XCC_ID)" : "=s"(xcd));
  xcd &= 7;

  // ---- one-time W preload: f32 global -> f16 LDS (padded rows) ----
  if (isL0) {
    for (int it = 0; it < 128; ++it) {
      int e = it * 512 + tid;
      int r = e >> 10, k = e & 1023;                 // LDS row r = gate*16 + u
      int grow = (r >> 4) * HID + j * 16 + (r & 15);
      *(f16*)(Wl + r * WROWB0 + 2 * k) = (f16)Whh0[(size_t)grow * HID + k];
    }
  } else {
    for (int it = 0; it < 128; ++it) {
      int e = it * 512 + tid;
      int r = e >> 11, k = e & 2047;                 // LDS row r = gate*8 + u
      int grow = (r >> 3) * HID + j * 8 + (r & 7);
      float v = (k < 1024) ? Wih1[(size_t)grow * HID + k]
                           : Whh1[(size_t)grow * HID + (k - 1024)];
      *(f16*)(Wl + r * WROWB1 + 2 * k) = (f16)v;
    }
    for (int e = tid; e < ZBYTES / 2; e += 512)      // shared zero band (N-pad)
      *(f16*)(Wl + ZOFF + 2 * e) = (f16)0.f;
  }

  // ---- per-lane constants ----
  float bi, bf, bg, bo, wi_i = 0, wi_f = 0, wi_g = 0, wi_o = 0, wl = 0;
  if (isL0) {
    int m = j * 16 + l15;
    bi = bih0[m] + bhh0[m];
    bf = bih0[HID + m] + bhh0[HID + m];
    bg = bih0[2 * HID + m] + bhh0[2 * HID + m];
    bo = bih0[3 * HID + m] + bhh0[3 * HID + m];
    wi_i = Wih0[m]; wi_f = Wih0[HID + m];
    wi_g = Wih0[2 * HID + m]; wi_o = Wih0[3 * HID + m];
  } else {
    int u = j * 8 + (l15 & 7);
    bi = bih1[u] + bhh1[u];
    bf = bih1[HID + u] + bhh1[HID + u];
    bg = bih1[2 * HID + u] + bhh1[2 * HID + u];
    bo = bih1[3 * HID + u] + bhh1[3 * HID + u];
    wl = (l15 < 8) ? Wlin[u] : 0.f;  // pad lanes contribute 0 to y
  }
  float cst[4];
#pragma unroll
  for (int q = 0; q < 4; ++q) cst[q] = 0.f;

  // ---- init: per-XCD block count cxa, rank within XCD (relay = rank 0),
  //      and nx = #XCDs present ----
  int cxa = 0, nx = 0, rank = 0;
  if (tid == 0) {
    rank = __hip_atomic_fetch_add(&sy[SY_CNTX + 32 * xcd], 1, __ATOMIC_RELAXED,
                                  __HIP_MEMORY_SCOPE_AGENT);
    __hip_atomic_fetch_add(&sy[SY_INIT], 1, __ATOMIC_RELAXED, __HIP_MEMORY_SCOPE_AGENT);
    spin_until(&sy[SY_INIT], NBLK);
    cxa = __hip_atomic_load(&sy[SY_CNTX + 32 * xcd], __ATOMIC_RELAXED,
                            __HIP_MEMORY_SCOPE_AGENT);
#pragma unroll
    for (int x = 0; x < 8; ++x)
      nx += (__hip_atomic_load(&sy[SY_CNTX + 32 * x], __ATOMIC_RELAXED,
                               __HIP_MEMORY_SCOPE_AGENT) > 0);
  }
  __syncthreads();

  // L0 B pointers: proven 16-unit layout (b tiles at +16/32/48 rows)
  const char* Wb = Wl + l15 * WROWB0 + lhi * 16;
  // L1 B pointers: one per gate; cols 8-15 -> shared zero band (B-frag = 0)
  const char* Wg0 = Wl + ((l15 < 8) ? (0 * 8 + l15) * WROWB1 : ZOFF) + lhi * 16;
  const char* Wg1 = Wl + ((l15 < 8) ? (1 * 8 + l15) * WROWB1 : ZOFF) + lhi * 16;
  const char* Wg2 = Wl + ((l15 < 8) ? (2 * 8 + l15) * WROWB1 : ZOFF) + lhi * 16;
  const char* Wg3 = Wl + ((l15 < 8) ? (3 * 8 + l15) * WROWB1 : ZOFF) + lhi * 16;

  for (int i = 1; i <= SEQ + 1; ++i) {
    // ---- joint step wait (top of iter) with relay broadcast ----
    // relay (rank 0 on its XCD): polls BG (<=8 pollers chip-wide), publishes
    // the completed iter to this XCD's GO line. Others poll GO (<=23/line).
    if (i >= 2) {
      if (tid == 0) {
        if (rank == 0) {
          spin_until(&sy[SY_BG], nx * (i - 1));
          __hip_atomic_store(&sy[SY_GO + 32 * xcd], i - 1, __ATOMIC_RELAXED,
                             __HIP_MEMORY_SCOPE_AGENT);
        } else {
          spin_until(&sy[SY_GO + 32 * xcd], i - 1);
        }
      }
      __syncthreads();
    }

    const bool active = isL0 ? (i <= SEQ) : (i >= 2);
    if (active) {
      // reads: slot i-1 (written last iter); writes: slot i (virgin addresses)
      const char* Asrc = (const char*)(Hbuf + (size_t)(i - 1) * SLOTE);
      char* Hw = (char*)(Hbuf + (size_t)i * SLOTE);
      const char* a0p = Asrc + (size_t)(16 * w + l15) * HROWB + lhi * 16;

      if (isL0) {
        // ----- layer0: 0-idx step i-1, K=1024 (h0 half), 4 gate-tiles -----
        float xr[4];
#pragma unroll
        for (int r = 0; r < 4; ++r)
          xr[r] = X[(16 * w + 4 * lhi + r) * SEQ + (i - 1)];

        half8 pa[8];
#pragma unroll
        for (int k0 = 0; k0 < 8; ++k0) pa[k0] = *(const half8*)(a0p + k0 * 64);
        f32x4 acc[4];
#pragma unroll
        for (int n = 0; n < 4; ++n) acc[n] = f32x4{0.f, 0.f, 0.f, 0.f};

#pragma unroll
        for (int ck = 0; ck < 32; ++ck) {
          half8 a0 = pa[ck & 7];
          if (ck < 24) pa[ck & 7] = *(const half8*)(a0p + (ck + 8) * 64);
          half8 b0 = *(const half8*)(Wb + ck * 64);
          half8 b1 = *(const half8*)(Wb + 16 * WROWB0 + ck * 64);
          half8 b2 = *(const half8*)(Wb + 32 * WROWB0 + ck * 64);
          half8 b3 = *(const half8*)(Wb + 48 * WROWB0 + ck * 64);
          acc[0] = __builtin_amdgcn_mfma_f32_16x16x32_f16(a0, b0, acc[0], 0, 0, 0);
          acc[1] = __builtin_amdgcn_mfma_f32_16x16x32_f16(a0, b1, acc[1], 0, 0, 0);
          acc[2] = __builtin_amdgcn_mfma_f32_16x16x32_f16(a0, b2, acc[2], 0, 0, 0);
          acc[3] = __builtin_amdgcn_mfma_f32_16x16x32_f16(a0, b3, acc[3], 0, 0, 0);
        }

        // cell update -> per-wave LDS bounce [16 rows][16 cols] f16 (512B)
#pragma unroll
        for (int r = 0; r < 4; ++r) {
          float xv = xr[r];
          float gi = acc[0][r] + bi + xv * wi_i;
          float gf = acc[1][r] + bf + xv * wi_f;
          float gg = acc[2][r] + bg + xv * wi_g;
          float go = acc[3][r] + bo + xv * wi_o;
          float cn = sigm(gf) * cst[r] + sigm(gi) * tanh_(gg);
          float hn = sigm(go) * tanh_(cn);
          cst[r] = cn;
          *(f16*)(Pk + w * 512 + (4 * lhi + r) * 32 + l15 * 2) = (f16)hn;
        }
        asm volatile("s_waitcnt lgkmcnt(0)" ::: "memory");  // wave-local LDS done
        {
          // lane l pushes 8B: row l>>2, quarter l&3
          u64 v = *(const u64*)(Pk + w * 512 + (l >> 2) * 32 + (l & 3) * 8);
          char* dst = Hw + (size_t)(16 * w + (l >> 2)) * HROWB + j * 32 + (l & 3) * 8;
          push8(dst, v);
        }
      } else {
        // ----- layer1: 0-idx step i-2, K=2048 full [h0|h1] row, 4 gate-tiles -----
        half8 pa[16];
#pragma unroll
        for (int k0 = 0; k0 < 16; ++k0) pa[k0] = *(const half8*)(a0p + k0 * 64);
        f32x4 acc[4];
#pragma unroll
        for (int n = 0; n < 4; ++n) acc[n] = f32x4{0.f, 0.f, 0.f, 0.f};

#pragma unroll
        for (int ck = 0; ck < 64; ++ck) {
          half8 a0 = pa[ck & 15];
          if (ck < 48) pa[ck & 15] = *(const half8*)(a0p + (ck + 16) * 64);
          half8 b0 = *(const half8*)(Wg0 + ck * 64);
          half8 b1 = *(const half8*)(Wg1 + ck * 64);
          half8 b2 = *(const half8*)(Wg2 + ck * 64);
          half8 b3 = *(const half8*)(Wg3 + ck * 64);
          acc[0] = __builtin_amdgcn_mfma_f32_16x16x32_f16(a0, b0, acc[0], 0, 0, 0);
          acc[1] = __builtin_amdgcn_mfma_f32_16x16x32_f16(a0, b1, acc[1], 0, 0, 0);
          acc[2] = __builtin_amdgcn_mfma_f32_16x16x32_f16(a0, b2, acc[2], 0, 0, 0);
          acc[3] = __builtin_amdgcn_mfma_f32_16x16x32_f16(a0, b3, acc[3], 0, 0, 0);
        }

        // Proven epilogue: all four gates lane-local, no exchange.
#pragma unroll
        for (int r = 0; r < 4; ++r) {
          int b = 16 * w + 4 * lhi + r;
          float gi = acc[0][r] + bi;
          float gf = acc[1][r] + bf;
          float gg = acc[2][r] + bg;
          float go = acc[3][r] + bo;
          float cn = sigm(gf) * cst[r] + sigm(gi) * tanh_(gg);
          float hn = sigm(go) * tanh_(cn);
          cst[r] = cn;
          if (l15 < 8)
            *(f16*)(Pk + w * 512 + (4 * lhi + r) * 16 + l15 * 2) = (f16)hn;
          float v = hn * wl;  // wl == 0 on pad lanes
          v += __shfl_xor(v, 1);
          v += __shfl_xor(v, 2);
          v += __shfl_xor(v, 4);
          v += __shfl_xor(v, 8);
          if (l15 == 0)
            yp[(size_t)(i - 2) * NBAT * NL1 + b * NL1 + j] = v;
        }
        asm volatile("s_waitcnt lgkmcnt(0)" ::: "memory");  // wave-local LDS done
        if (l < 32) {
          // lane l pushes 8B: row l>>1, half l&1
          u64 v = *(const u64*)(Pk + w * 512 + (l >> 1) * 16 + (l & 1) * 8);
          char* dst =
              Hw + (size_t)(16 * w + (l >> 1)) * HROWB + 2048 + j * 16 + (l & 1) * 8;
          push8(dst, v);
        }
      }
    }

    // ---- arrival (end of iter): per-XCD line (<=24 adders); last arriver
    //      on the XCD bumps BG (8 adds/step chip-wide). No spin here. ----
    if (i <= SEQ) {
      vm0();            // swaps acknowledged by the LLC
      __syncthreads();  // whole block done
      if (tid == 0) {
        int old = __hip_atomic_fetch_add(&sy[SY_BARX + 32 * xcd], 1, __ATOMIC_RELAXED,
                                         __HIP_MEMORY_SCOPE_AGENT);
        if (old == cxa * i - 1)
          __hip_atomic_fetch_add(&sy[SY_BG], 1, __ATOMIC_RELAXED,
                                 __HIP_MEMORY_SCOPE_AGENT);
      }
    }
  }
}

__global__ __launch_bounds__(256) void zero_ws(f16* Hbuf, int* sy) {
  int g = blockIdx.x * 256 + threadIdx.x, gs = gridDim.x * 256;
  // zero slots 0 (read at iter 1) and 1 (h1 half read at iter 2)
  for (size_t idx = g; idx < 2 * SLOTE; idx += gs) Hbuf[idx] = (f16)0.f;
  for (int idx = g; idx < 1024; idx += gs) sy[idx] = 0;
}

__global__ __launch_bounds__(256) void final_kernel(const float* __restrict__ yp,
                                                    const float* __restrict__ blin,
                                                    float* __restrict__ out) {
  const int idx = blockIdx.x * blockDim.x + threadIdx.x;  // 0..32767
  const int t = idx >> 7, b = idx & 127;
  const float* p = yp + ((size_t)t * NBAT + b) * NL1;
  float s = 0.f;
#pragma unroll
  for (int q = 0; q < NL1; ++q) s += p[q];
  out[b * SEQ + t] = s + blin[0];
}

extern "C" void kernel_launch(void* const* d_in, const int* in_sizes, int n_in,
                              void* d_out, int out_size, void* d_ws, size_t ws_size,
                              hipStream_t stream) {
  const float* X = (const float*)d_in[0];
  const float* Wih0 = (const float*)d_in[1];
  const float* Whh0 = (const float*)d_in[2];
  const float* bih0 = (const float*)d_in[3];
  const float* bhh0 = (const float*)d_in[4];
  const float* Wih1 = (const float*)d_in[5];
  const float* Whh1 = (const float*)d_in[6];
  const float* bih1 = (const float*)d_in[7];
  const float* bhh1 = (const float*)d_in[8];
  const float* Wlin = (const float*)d_in[9];
  const float* blin = (const float*)d_in[10];
  float* out = (float*)d_out;

  char* p = (char*)d_ws;
  f16* Hbuf = (f16*)p;    p += (size_t)NSLOT * SLOTE * 2;        // 132 MB
  float* yp = (float*)p;  p += (size_t)SEQ * NBAT * NL1 * 4;     // 16.8 MB
  int* sy = (int*)p;      p += 1024 * 4;

  hipFuncSetAttribute((const void*)lstm_persist,
                      hipFuncAttributeMaxDynamicSharedMemorySize, LDS_TOTAL);

  zero_ws<<<256, 256, 0, stream>>>(Hbuf, sy);

  lstm_persist<<<NBLK, 512, LDS_TOTAL, stream>>>(
      X, Wih0, Whh0, bih0, bhh0, Wih1, Whh1, bih1, bhh1, Wlin,
      Hbuf, yp, sy);

  final_kernel<<<NBAT, 256, 0, stream>>>(yp, blin, out);
}

// Round 17
// 4689.359 us; speedup vs baseline: 1.8315x; 1.0041x over previous
//
#include <hip/hip_runtime.h>
#include <stdint.h>

typedef _Float16 f16;
typedef f16 half8 __attribute__((ext_vector_type(8)));
typedef float f32x4 __attribute__((ext_vector_type(4)));
typedef unsigned long long u64;

constexpr int HID = 1024;
constexpr int NBAT = 128;
constexpr int SEQ = 256;
constexpr int NL0 = 64;          // layer0 blocks: 16 units, K=1024
constexpr int NL1 = 128;         // layer1 blocks: 8 units,  K=2048 ([Wih1|Whh1])
constexpr int NBLK = NL0 + NL1;  // 192
constexpr int HROWB = 4096;      // slot row bytes: [h0(1024) | h1(1024)] f16
constexpr int NSLOT = 258;       // rotating h slots (virgin addresses each step)
constexpr size_t SLOTE = (size_t)NBAT * 2048;  // f16 elems per slot
constexpr int WROWB0 = 2064;     // L0 LDS W row: 2048B + 16 pad
constexpr int WROWB1 = 4112;     // L1 LDS W row: 4096B + 16 pad
constexpr int ZOFF = 32 * WROWB1;    // 131584: start of shared zero band (L1)
constexpr int ZBYTES = 4160;         // covers ck*64 + lhi*16 (<= 4080) + slack
constexpr int WLDS = ZOFF + ZBYTES;  // 135744 >= 64*WROWB0 (132096)
constexpr int LDS_TOTAL = WLDS + 4096;  // + per-wave h-repack bounce (8 x 512B)

// sync buffer layout (ints; 128B line separation)
constexpr int SY_INIT = 0;        // one-time init barrier
constexpr int SY_BG = 32;         // global "XCD complete" counter (accumulating)
constexpr int SY_CNTX = 64;       // +32*x: blocks on XCD x
constexpr int SY_BARX = 320;      // +32*x: per-XCD arrivals (accumulating)

__device__ __forceinline__ float sigm(float x) { return 1.0f / (1.0f + __expf(-x)); }
__device__ __forceinline__ float tanh_(float x) {
  float e = __expf(2.0f * x);
  return (e - 1.0f) / (e + 1.0f);
}
__device__ __forceinline__ void vm0() {
  asm volatile("s_waitcnt vmcnt(0)" ::: "memory");
}
// h push: agent-scope atomic exchange executes at the LLC (coherence point) —
// the op class proven coherent by every barrier/flag in rounds 2-16.
__device__ __forceinline__ void push8(void* dst, u64 v) {
  (void)__hip_atomic_exchange((u64*)dst, v, __ATOMIC_RELAXED, __HIP_MEMORY_SCOPE_AGENT);
}
__device__ __forceinline__ void spin_until(int* p, int target) {
  uint64_t t0 = __builtin_amdgcn_s_memtime();
  while (__hip_atomic_load(p, __ATOMIC_RELAXED, __HIP_MEMORY_SCOPE_AGENT) < target) {
    __builtin_amdgcn_s_sleep(1);
    if (__builtin_amdgcn_s_memtime() - t0 > (1ULL << 29)) break;  // bounded on pathology
  }
}

// 512 threads = 8 waves (2/SIMD); each wave owns ONE 16-row m-frag.
__global__ __launch_bounds__(512, 1) void lstm_persist(
    const float* __restrict__ X,
    const float* __restrict__ Wih0, const float* __restrict__ Whh0,
    const float* __restrict__ bih0, const float* __restrict__ bhh0,
    const float* __restrict__ Wih1, const float* __restrict__ Whh1,
    const float* __restrict__ bih1, const float* __restrict__ bhh1,
    const float* __restrict__ Wlin,
    f16* __restrict__ Hbuf,   // [NSLOT][128][2048]  rotating slots
    float* __restrict__ yp,   // [256][128][128] per-L1-block y partials
    int* __restrict__ sy) {
  extern __shared__ char smem[];
  char* Wl = smem;
  char* Pk = smem + WLDS;   // per-wave h repack bounce (w*512)

  const int bid = blockIdx.x, tid = threadIdx.x;
  const bool isL0 = bid < NL0;
  const int j = isL0 ? bid : bid - NL0;
  const int w = tid >> 6, l = tid & 63;
  const int l15 = l & 15, lhi = l >> 4;

  int xcd;
  asm volatile("s_getreg_b32 %0, hwreg(HW_REG_XCC_ID)" : "=s"(xcd));
  xcd &= 7;

  // ---- one-time W preload: f32 global -> f16 LDS (padded rows) ----
  if (isL0) {
    for (int it = 0; it < 128; ++it) {
      int e = it * 512 + tid;
      int r = e >> 10, k = e & 1023;                 // LDS row r = gate*16 + u
      int grow = (r >> 4) * HID + j * 16 + (r & 15);
      *(f16*)(Wl + r * WROWB0 + 2 * k) = (f16)Whh0[(size_t)grow * HID + k];
    }
  } else {
    for (int it = 0; it < 128; ++it) {
      int e = it * 512 + tid;
      int r = e >> 11, k = e & 2047;                 // LDS row r = gate*8 + u
      int grow = (r >> 3) * HID + j * 8 + (r & 7);
      float v = (k < 1024) ? Wih1[(size_t)grow * HID + k]
                           : Whh1[(size_t)grow * HID + (k - 1024)];
      *(f16*)(Wl + r * WROWB1 + 2 * k) = (f16)v;
    }
    for (int e = tid; e < ZBYTES / 2; e += 512)      // shared zero band (N-pad)
      *(f16*)(Wl + ZOFF + 2 * e) = (f16)0.f;
  }

  // ---- per-lane constants ----
  float bi, bf, bg, bo, wi_i = 0, wi_f = 0, wi_g = 0, wi_o = 0, wl = 0;
  if (isL0) {
    int m = j * 16 + l15;
    bi = bih0[m] + bhh0[m];
    bf = bih0[HID + m] + bhh0[HID + m];
    bg = bih0[2 * HID + m] + bhh0[2 * HID + m];
    bo = bih0[3 * HID + m] + bhh0[3 * HID + m];
    wi_i = Wih0[m]; wi_f = Wih0[HID + m];
    wi_g = Wih0[2 * HID + m]; wi_o = Wih0[3 * HID + m];
  } else {
    int u = j * 8 + (l15 & 7);
    bi = bih1[u] + bhh1[u];
    bf = bih1[HID + u] + bhh1[HID + u];
    bg = bih1[2 * HID + u] + bhh1[2 * HID + u];
    bo = bih1[3 * HID + u] + bhh1[3 * HID + u];
    wl = (l15 < 8) ? Wlin[u] : 0.f;  // pad lanes contribute 0 to y
  }
  float cst[4];
#pragma unroll
  for (int q = 0; q < 4; ++q) cst[q] = 0.f;

  // ---- init: per-XCD block count cxa and nx = #XCDs present ----
  int cxa = 0, nx = 0;
  if (tid == 0) {
    __hip_atomic_fetch_add(&sy[SY_CNTX + 32 * xcd], 1, __ATOMIC_RELAXED,
                           __HIP_MEMORY_SCOPE_AGENT);
    __hip_atomic_fetch_add(&sy[SY_INIT], 1, __ATOMIC_RELAXED, __HIP_MEMORY_SCOPE_AGENT);
    spin_until(&sy[SY_INIT], NBLK);
    cxa = __hip_atomic_load(&sy[SY_CNTX + 32 * xcd], __ATOMIC_RELAXED,
                            __HIP_MEMORY_SCOPE_AGENT);
#pragma unroll
    for (int x = 0; x < 8; ++x)
      nx += (__hip_atomic_load(&sy[SY_CNTX + 32 * x], __ATOMIC_RELAXED,
                               __HIP_MEMORY_SCOPE_AGENT) > 0);
  }
  __syncthreads();

  // L0 B pointers: proven 16-unit layout (b tiles at +16/32/48 rows)
  const char* Wb = Wl + l15 * WROWB0 + lhi * 16;
  // L1 B pointers: one per gate; cols 8-15 -> shared zero band (B-frag = 0)
  const char* Wg0 = Wl + ((l15 < 8) ? (0 * 8 + l15) * WROWB1 : ZOFF) + lhi * 16;
  const char* Wg1 = Wl + ((l15 < 8) ? (1 * 8 + l15) * WROWB1 : ZOFF) + lhi * 16;
  const char* Wg2 = Wl + ((l15 < 8) ? (2 * 8 + l15) * WROWB1 : ZOFF) + lhi * 16;
  const char* Wg3 = Wl + ((l15 < 8) ? (3 * 8 + l15) * WROWB1 : ZOFF) + lhi * 16;

  for (int i = 1; i <= SEQ + 1; ++i) {
    // ---- joint step wait (top of iter): single spin, no relay (R11-proven;
    //      R16 showed poller fan-out is irrelevant) ----
    if (i >= 2) {
      if (tid == 0) spin_until(&sy[SY_BG], nx * (i - 1));
      __syncthreads();
    }

    const bool active = isL0 ? (i <= SEQ) : (i >= 2);
    if (active) {
      // reads: slot i-1 (written last iter); writes: slot i (virgin addresses)
      const char* Asrc = (const char*)(Hbuf + (size_t)(i - 1) * SLOTE);
      char* Hw = (char*)(Hbuf + (size_t)i * SLOTE);
      const char* a0p = Asrc + (size_t)(16 * w + l15) * HROWB + lhi * 16;

      if (isL0) {
        // ----- layer0: 0-idx step i-1, K=1024 (h0 half), 4 gate-tiles -----
        float xr[4];
#pragma unroll
        for (int r = 0; r < 4; ++r)
          xr[r] = X[(16 * w + 4 * lhi + r) * SEQ + (i - 1)];

        // full preload: all 32 chunks in flight (one serial LLC round)
        half8 pa[32];
#pragma unroll
        for (int k0 = 0; k0 < 32; ++k0) pa[k0] = *(const half8*)(a0p + k0 * 64);
        f32x4 acc[4];
#pragma unroll
        for (int n = 0; n < 4; ++n) acc[n] = f32x4{0.f, 0.f, 0.f, 0.f};

#pragma unroll
        for (int ck = 0; ck < 32; ++ck) {
          half8 a0 = pa[ck];
          half8 b0 = *(const half8*)(Wb + ck * 64);
          half8 b1 = *(const half8*)(Wb + 16 * WROWB0 + ck * 64);
          half8 b2 = *(const half8*)(Wb + 32 * WROWB0 + ck * 64);
          half8 b3 = *(const half8*)(Wb + 48 * WROWB0 + ck * 64);
          acc[0] = __builtin_amdgcn_mfma_f32_16x16x32_f16(a0, b0, acc[0], 0, 0, 0);
          acc[1] = __builtin_amdgcn_mfma_f32_16x16x32_f16(a0, b1, acc[1], 0, 0, 0);
          acc[2] = __builtin_amdgcn_mfma_f32_16x16x32_f16(a0, b2, acc[2], 0, 0, 0);
          acc[3] = __builtin_amdgcn_mfma_f32_16x16x32_f16(a0, b3, acc[3], 0, 0, 0);
        }

        // cell update -> per-wave LDS bounce [16 rows][16 cols] f16 (512B)
#pragma unroll
        for (int r = 0; r < 4; ++r) {
          float xv = xr[r];
          float gi = acc[0][r] + bi + xv * wi_i;
          float gf = acc[1][r] + bf + xv * wi_f;
          float gg = acc[2][r] + bg + xv * wi_g;
          float go = acc[3][r] + bo + xv * wi_o;
          float cn = sigm(gf) * cst[r] + sigm(gi) * tanh_(gg);
          float hn = sigm(go) * tanh_(cn);
          cst[r] = cn;
          *(f16*)(Pk + w * 512 + (4 * lhi + r) * 32 + l15 * 2) = (f16)hn;
        }
        asm volatile("s_waitcnt lgkmcnt(0)" ::: "memory");  // wave-local LDS done
        {
          // lane l pushes 8B: row l>>2, quarter l&3
          u64 v = *(const u64*)(Pk + w * 512 + (l >> 2) * 32 + (l & 3) * 8);
          char* dst = Hw + (size_t)(16 * w + (l >> 2)) * HROWB + j * 32 + (l & 3) * 8;
          push8(dst, v);
        }
      } else {
        // ----- layer1: 0-idx step i-2, K=2048 full [h0|h1] row, 4 gate-tiles -----
        // ring depth 32: 64 chunks -> 2 serial LLC rounds
        half8 pa[32];
#pragma unroll
        for (int k0 = 0; k0 < 32; ++k0) pa[k0] = *(const half8*)(a0p + k0 * 64);
        f32x4 acc[4];
#pragma unroll
        for (int n = 0; n < 4; ++n) acc[n] = f32x4{0.f, 0.f, 0.f, 0.f};

#pragma unroll
        for (int ck = 0; ck < 64; ++ck) {
          half8 a0 = pa[ck & 31];
          if (ck < 32) pa[ck & 31] = *(const half8*)(a0p + (ck + 32) * 64);
          half8 b0 = *(const half8*)(Wg0 + ck * 64);
          half8 b1 = *(const half8*)(Wg1 + ck * 64);
          half8 b2 = *(const half8*)(Wg2 + ck * 64);
          half8 b3 = *(const half8*)(Wg3 + ck * 64);
          acc[0] = __builtin_amdgcn_mfma_f32_16x16x32_f16(a0, b0, acc[0], 0, 0, 0);
          acc[1] = __builtin_amdgcn_mfma_f32_16x16x32_f16(a0, b1, acc[1], 0, 0, 0);
          acc[2] = __builtin_amdgcn_mfma_f32_16x16x32_f16(a0, b2, acc[2], 0, 0, 0);
          acc[3] = __builtin_amdgcn_mfma_f32_16x16x32_f16(a0, b3, acc[3], 0, 0, 0);
        }

        // Proven epilogue: all four gates lane-local, no exchange.
#pragma unroll
        for (int r = 0; r < 4; ++r) {
          int b = 16 * w + 4 * lhi + r;
          float gi = acc[0][r] + bi;
          float gf = acc[1][r] + bf;
          float gg = acc[2][r] + bg;
          float go = acc[3][r] + bo;
          float cn = sigm(gf) * cst[r] + sigm(gi) * tanh_(gg);
          float hn = sigm(go) * tanh_(cn);
          cst[r] = cn;
          if (l15 < 8)
            *(f16*)(Pk + w * 512 + (4 * lhi + r) * 16 + l15 * 2) = (f16)hn;
          float v = hn * wl;  // wl == 0 on pad lanes
          v += __shfl_xor(v, 1);
          v += __shfl_xor(v, 2);
          v += __shfl_xor(v, 4);
          v += __shfl_xor(v, 8);
          if (l15 == 0)
            yp[(size_t)(i - 2) * NBAT * NL1 + b * NL1 + j] = v;
        }
        asm volatile("s_waitcnt lgkmcnt(0)" ::: "memory");  // wave-local LDS done
        if (l < 32) {
          // lane l pushes 8B: row l>>1, half l&1
          u64 v = *(const u64*)(Pk + w * 512 + (l >> 1) * 16 + (l & 1) * 8);
          char* dst =
              Hw + (size_t)(16 * w + (l >> 1)) * HROWB + 2048 + j * 16 + (l & 1) * 8;
          push8(dst, v);
        }
      }
    }

    // ---- arrival (end of iter): per-XCD line; last arriver bumps BG.
    //      No spin here. ----
    if (i <= SEQ) {
      vm0();            // swaps acknowledged by the LLC
      __syncthreads();  // whole block done
      if (tid == 0) {
        int old = __hip_atomic_fetch_add(&sy[SY_BARX + 32 * xcd], 1, __ATOMIC_RELAXED,
                                         __HIP_MEMORY_SCOPE_AGENT);
        if (old == cxa * i - 1)
          __hip_atomic_fetch_add(&sy[SY_BG], 1, __ATOMIC_RELAXED,
                                 __HIP_MEMORY_SCOPE_AGENT);
      }
    }
  }
}

__global__ __launch_bounds__(256) void zero_ws(f16* Hbuf, int* sy) {
  int g = blockIdx.x * 256 + threadIdx.x, gs = gridDim.x * 256;
  // zero slots 0 (read at iter 1) and 1 (h1 half read at iter 2)
  for (size_t idx = g; idx < 2 * SLOTE; idx += gs) Hbuf[idx] = (f16)0.f;
  for (int idx = g; idx < 1024; idx += gs) sy[idx] = 0;
}

__global__ __launch_bounds__(256) void final_kernel(const float* __restrict__ yp,
                                                    const float* __restrict__ blin,
                                                    float* __restrict__ out) {
  const int idx = blockIdx.x * blockDim.x + threadIdx.x;  // 0..32767
  const int t = idx >> 7, b = idx & 127;
  const float* p = yp + ((size_t)t * NBAT + b) * NL1;
  float s = 0.f;
#pragma unroll
  for (int q = 0; q < NL1; ++q) s += p[q];
  out[b * SEQ + t] = s + blin[0];
}

extern "C" void kernel_launch(void* const* d_in, const int* in_sizes, int n_in,
                              void* d_out, int out_size, void* d_ws, size_t ws_size,
                              hipStream_t stream) {
  const float* X = (const float*)d_in[0];
  const float* Wih0 = (const float*)d_in[1];
  const float* Whh0 = (const float*)d_in[2];
  const float* bih0 = (const float*)d_in[3];
  const float* bhh0 = (const float*)d_in[4];
  const float* Wih1 = (const float*)d_in[5];
  const float* Whh1 = (const float*)d_in[6];
  const float* bih1 = (const float*)d_in[7];
  const float* bhh1 = (const float*)d_in[8];
  const float* Wlin = (const float*)d_in[9];
  const float* blin = (const float*)d_in[10];
  float* out = (float*)d_out;

  char* p = (char*)d_ws;
  f16* Hbuf = (f16*)p;    p += (size_t)NSLOT * SLOTE * 2;        // 132 MB
  float* yp = (float*)p;  p += (size_t)SEQ * NBAT * NL1 * 4;     // 16.8 MB
  int* sy = (int*)p;      p += 1024 * 4;

  hipFuncSetAttribute((const void*)lstm_persist,
                      hipFuncAttributeMaxDynamicSharedMemorySize, LDS_TOTAL);

  zero_ws<<<256, 256, 0, stream>>>(Hbuf, sy);

  lstm_persist<<<NBLK, 512, LDS_TOTAL, stream>>>(
      X, Wih0, Whh0, bih0, bhh0, Wih1, Whh1, bih1, bhh1, Wlin,
      Hbuf, yp, sy);

  final_kernel<<<NBAT, 256, 0, stream>>>(yp, blin, out);
}